// Round 10
// baseline (73.123 us; speedup 1.0000x reference)
//
#include <hip/hip_runtime.h>

// Chamfer-style point loss via MFMA 16x16x32 bf16 (layout VERIFIED R5/R9,
// absmax 0.0): B=16, N=4096, F=3.
// elem(i,j) = x_i.y_j - sqx_i/2 - sqy_j/2 = -D_ij/2 ; min_j D = -2 max_j elem.
// R10: <=64-VGPR wave (1 i-tile, swap-free double-body pipeline) to unlock
// 8 waves/SIMD — R9's 4 waves could not cover L2 latency.

constexpr int B_ = 16;
constexpr int N_ = 4096;
constexpr int BN = B_ * N_;          // 65536
constexpr int BLK = 256;
constexpr int JT = N_ / 16;          // 256 j-tiles, all j per block

using bf16x8 = __attribute__((ext_vector_type(8))) __bf16;
using f32x4  = __attribute__((ext_vector_type(4))) float;

__device__ inline uint bf16_rne(float f) {
    uint u = __float_as_uint(f);
    return (u + 0x7FFFu + ((u >> 16) & 1u)) >> 16;
}
__device__ inline float bf16_f(uint h) { return __uint_as_float(h << 16); }

// K-slot packing (16 bf16 = 32B per point, per role) — identical to R5:
// A-row (X): [hx,hy,hz, lx,ly,lz, hx,hy | hz, 1, 1, thx, tlx, 0,0,0]
// B-col (Y): [hx,hy,hz, hx,hy,hz, lx,ly | lz, thy, tly, 1, 1, 0,0,0]
__global__ __launch_bounds__(BLK)
void prep_kernel(const float* __restrict__ a1, const float* __restrict__ a2,
                 uint4* __restrict__ A1, uint4* __restrict__ B1,
                 uint4* __restrict__ A2, uint4* __restrict__ B2) {
    int gi = blockIdx.x * BLK + threadIdx.x;           // [0, BN)
    const float* in = blockIdx.y ? a2 : a1;
    uint4* Ao = blockIdx.y ? A2 : A1;
    uint4* Bo = blockIdx.y ? B2 : B1;
    float x = in[3 * gi], y = in[3 * gi + 1], z = in[3 * gi + 2];
    float sq = fmaf(x, x, fmaf(y, y, z * z));
    float t = -0.5f * sq;
    uint hx = bf16_rne(x), hy = bf16_rne(y), hz = bf16_rne(z);
    uint lx = bf16_rne(x - bf16_f(hx));
    uint ly = bf16_rne(y - bf16_f(hy));
    uint lz = bf16_rne(z - bf16_f(hz));
    uint th = bf16_rne(t);
    uint tl = bf16_rne(t - bf16_f(th));
    const uint ONE = 0x3F80u;
    Ao[2 * gi]     = make_uint4(hx | (hy << 16), hz | (lx << 16), ly | (lz << 16), hx | (hy << 16));
    Ao[2 * gi + 1] = make_uint4(hz | (ONE << 16), ONE | (th << 16), tl, 0u);
    Bo[2 * gi]     = make_uint4(hx | (hy << 16), hz | (hx << 16), hy | (hz << 16), lx | (ly << 16));
    Bo[2 * gi + 1] = make_uint4(lz | (th << 16), tl | (ONE << 16), ONE, 0u);
}

// 4 j-tiles folded: 4 independent MFMA + 8 max3 (fmaxf pairs fuse to v_max3).
#define FOLD4(Q0, Q1, Q2, Q3) {                                                  \
    f32x4 oA = __builtin_amdgcn_mfma_f32_16x16x32_bf16(a0, (Q0), cz, 0, 0, 0);   \
    f32x4 oB = __builtin_amdgcn_mfma_f32_16x16x32_bf16(a0, (Q1), cz, 0, 0, 0);   \
    f32x4 oC = __builtin_amdgcn_mfma_f32_16x16x32_bf16(a0, (Q2), cz, 0, 0, 0);   \
    f32x4 oD = __builtin_amdgcn_mfma_f32_16x16x32_bf16(a0, (Q3), cz, 0, 0, 0);   \
    _Pragma("unroll")                                                            \
    for (int r = 0; r < 4; ++r) {                                                \
        vm0[r] = fmaxf(fmaxf(vm0[r], oA[r]), oB[r]);                             \
        vm0[r] = fmaxf(fmaxf(vm0[r], oC[r]), oD[r]);                             \
    } }

// grid: (N/64=64, B=16, 2) = 2048 blocks = 8 blocks/CU = 8 waves/SIMD.
// Wave: ONE 16-i tile, ALL 256 j-tiles; fused block reduction.
__global__ __launch_bounds__(BLK, 8)
void minmax_kernel(const uint4* __restrict__ A1u, const uint4* __restrict__ B1u,
                   const uint4* __restrict__ A2u, const uint4* __restrict__ B2u,
                   float* __restrict__ bsums) {
    int d = blockIdx.z, b = blockIdx.y;
    const bf16x8* __restrict__ Aarr = (const bf16x8*)(d ? A2u : A1u);
    const bf16x8* __restrict__ Barr = (const bf16x8*)(d ? B1u : B2u);
    int tid = threadIdx.x;
    int L = tid & 63, w = tid >> 6;
    int lpt = L & 15, hi = (L >> 4) & 1;
    bool act = L < 32;                                 // k-groups 2,3 are zero
    int ibase = blockIdx.x * 64 + w * 16;              // i within batch row

    const bf16x8* pA = Aarr + (size_t)(b * N_ + ibase + lpt) * 2 + hi;
    const bf16x8* pB = Barr + (size_t)(b * N_ + lpt) * 2 + hi;

    uint4 zu; zu.x = zu.y = zu.z = zu.w = 0u;
    bf16x8 zf = __builtin_bit_cast(bf16x8, zu);
    bf16x8 a0 = act ? pA[0] : zf;
    f32x4 cz = {0.f, 0.f, 0.f, 0.f};
    f32x4 vm0 = {-3.0e38f, -3.0e38f, -3.0e38f, -3.0e38f};

    // Swap-free double-body pipeline: loads land directly in the bank being
    // refilled; 4 tiles in flight while 4 compute. No v_mov swaps.
    bf16x8 p0 = pB[0], p1 = pB[32], p2 = pB[64], p3 = pB[96];
#pragma unroll 1
    for (int jt = 0; jt + 8 < JT; jt += 8) {
        const bf16x8* q = pB + (size_t)jt * 32;
        bf16x8 n0 = q[128], n1 = q[160], n2 = q[192], n3 = q[224];
        FOLD4(p0, p1, p2, p3)
        p0 = q[256]; p1 = q[288]; p2 = q[320]; p3 = q[352];
        FOLD4(n0, n1, n2, n3)
    }
    {   // tiles 248..255 (p0..p3 = 248..251 already loaded)
        const bf16x8* q = pB + (size_t)248 * 32;
        bf16x8 n0 = q[128], n1 = q[160], n2 = q[192], n3 = q[224];
        FOLD4(p0, p1, p2, p3)
        FOLD4(n0, n1, n2, n3)
    }

    // butterfly max across the 16 "col" (j) lanes — verified epilogue
#pragma unroll
    for (int off = 1; off < 16; off <<= 1)
#pragma unroll
        for (int r = 0; r < 4; ++r)
            vm0[r] = fmaxf(vm0[r], __shfl_xor(vm0[r], off));

    // Fused sum (R9-verified): lane group g=(L>>4) holds rowmax[g*4+r].
    float v = (vm0[0] + vm0[1]) + (vm0[2] + vm0[3]);
    v += __shfl_xor(v, 16);
    v += __shfl_xor(v, 32);                            // wave total

    __shared__ float red4[4];
    if (L == 0) red4[w] = v;
    __syncthreads();
    if (tid == 0) {
        int bid = blockIdx.x + 64 * blockIdx.y + 1024 * blockIdx.z;
        bsums[bid] = red4[0] + red4[1] + red4[2] + red4[3];
    }
}

// 2048 block sums -> scalar.  out = sum * (-2) * 100 * 0.5 / BN = sum * -100/BN
__global__ __launch_bounds__(BLK)
void reduce_final(const float* __restrict__ bs, float* __restrict__ out) {
    int t = threadIdx.x;
    float v = 0.f;
#pragma unroll
    for (int k = 0; k < 8; ++k) v += bs[t + 256 * k];
    for (int off = 32; off; off >>= 1) v += __shfl_down(v, off, 64);
    __shared__ float red4[4];
    int lane = t & 63, w = t >> 6;
    if (lane == 0) red4[w] = v;
    __syncthreads();
    if (t == 0) out[0] = (red4[0] + red4[1] + red4[2] + red4[3]) * (-100.0f / (float)BN);
}

extern "C" void kernel_launch(void* const* d_in, const int* in_sizes, int n_in,
                              void* d_out, int out_size, void* d_ws, size_t ws_size,
                              hipStream_t stream) {
    const float* a1 = (const float*)d_in[0];
    const float* a2 = (const float*)d_in[1];
    char* ws = (char*)d_ws;
    uint4* A1 = (uint4*)(ws);                          // 2 MB each
    uint4* B1 = (uint4*)(ws + (2u << 20));
    uint4* A2 = (uint4*)(ws + (4u << 20));
    uint4* B2 = (uint4*)(ws + (6u << 20));
    float* bsums = (float*)(ws + (8u << 20));          // 8 KB
    float* out = (float*)d_out;

    prep_kernel<<<dim3(BN / BLK, 2), BLK, 0, stream>>>(a1, a2, A1, B1, A2, B2);
    minmax_kernel<<<dim3(N_ / 64, B_, 2), BLK, 0, stream>>>(A1, B1, A2, B2, bsums);
    reduce_final<<<dim3(1), BLK, 0, stream>>>(bsums, out);
}

// Round 11
// 41.674 us; speedup vs baseline: 1.7546x; 1.7546x over previous
//
#include <hip/hip_runtime.h>

// Chamfer-style point loss via MFMA 16x16x32 bf16 (layout VERIFIED R5/R9):
// B=16, N=4096, F=3. elem(i,j) = x.y - sqx/2 - sqy/2 = -D/2.
// R10 lesson: per-wave j-stream is fixed (256KB); total load traffic scales
// with #waves => maximize i-tiles per wave. IPT=4 here (R9=2, R10=1).

constexpr int B_ = 16;
constexpr int N_ = 4096;
constexpr int BN = B_ * N_;          // 65536
constexpr int BLK = 256;
constexpr int JSPLIT = 2;
constexpr int JCHUNK = N_ / JSPLIT;  // 2048
constexpr int JT2 = JCHUNK / 16;     // 128 j-tiles per block

using bf16x8 = __attribute__((ext_vector_type(8))) __bf16;
using f32x4  = __attribute__((ext_vector_type(4))) float;

__device__ inline uint bf16_rne(float f) {
    uint u = __float_as_uint(f);
    return (u + 0x7FFFu + ((u >> 16) & 1u)) >> 16;
}
__device__ inline float bf16_f(uint h) { return __uint_as_float(h << 16); }

// K-slot packing (16 bf16 = 32B per point, per role) — identical to R5:
// A-row (X): [hx,hy,hz, lx,ly,lz, hx,hy | hz, 1, 1, thx, tlx, 0,0,0]
// B-col (Y): [hx,hy,hz, hx,hy,hz, lx,ly | lz, thy, tly, 1, 1, 0,0,0]
__global__ __launch_bounds__(BLK)
void prep_kernel(const float* __restrict__ a1, const float* __restrict__ a2,
                 uint4* __restrict__ A1, uint4* __restrict__ B1,
                 uint4* __restrict__ A2, uint4* __restrict__ B2) {
    int gi = blockIdx.x * BLK + threadIdx.x;           // [0, BN)
    const float* in = blockIdx.y ? a2 : a1;
    uint4* Ao = blockIdx.y ? A2 : A1;
    uint4* Bo = blockIdx.y ? B2 : B1;
    float x = in[3 * gi], y = in[3 * gi + 1], z = in[3 * gi + 2];
    float sq = fmaf(x, x, fmaf(y, y, z * z));
    float t = -0.5f * sq;
    uint hx = bf16_rne(x), hy = bf16_rne(y), hz = bf16_rne(z);
    uint lx = bf16_rne(x - bf16_f(hx));
    uint ly = bf16_rne(y - bf16_f(hy));
    uint lz = bf16_rne(z - bf16_f(hz));
    uint th = bf16_rne(t);
    uint tl = bf16_rne(t - bf16_f(th));
    const uint ONE = 0x3F80u;
    Ao[2 * gi]     = make_uint4(hx | (hy << 16), hz | (lx << 16), ly | (lz << 16), hx | (hy << 16));
    Ao[2 * gi + 1] = make_uint4(hz | (ONE << 16), ONE | (th << 16), tl, 0u);
    Bo[2 * gi]     = make_uint4(hx | (hy << 16), hz | (hx << 16), hy | (hz << 16), lx | (ly << 16));
    Bo[2 * gi + 1] = make_uint4(lz | (th << 16), tl | (ONE << 16), ONE, 0u);
}

// One j-tile folded into all 4 i-tile accumulators: 4 MFMA + 8 max3.
#define FOLD1(Q) {                                                               \
    f32x4 o0 = __builtin_amdgcn_mfma_f32_16x16x32_bf16(a0, (Q), cz, 0, 0, 0);    \
    f32x4 o1 = __builtin_amdgcn_mfma_f32_16x16x32_bf16(a1, (Q), cz, 0, 0, 0);    \
    f32x4 o2 = __builtin_amdgcn_mfma_f32_16x16x32_bf16(a2, (Q), cz, 0, 0, 0);    \
    f32x4 o3 = __builtin_amdgcn_mfma_f32_16x16x32_bf16(a3, (Q), cz, 0, 0, 0);    \
    _Pragma("unroll")                                                            \
    for (int r = 0; r < 4; ++r) {                                                \
        vm0[r] = fmaxf(fmaxf(vm0[r], o0[r]), o1[r]);                             \
        vm1[r] = fmaxf(fmaxf(vm1[r], o2[r]), o3[r]);                             \
    } }
// NOTE: vm0 accumulates i-tiles 0,1 jointly? NO — must stay separate per
// i-tile. See FOLDT below (kept separate).
#undef FOLD1

#define FOLDT(Q) {                                                               \
    f32x4 o0 = __builtin_amdgcn_mfma_f32_16x16x32_bf16(a0, (Q), cz, 0, 0, 0);    \
    f32x4 o1 = __builtin_amdgcn_mfma_f32_16x16x32_bf16(a1, (Q), cz, 0, 0, 0);    \
    f32x4 o2 = __builtin_amdgcn_mfma_f32_16x16x32_bf16(a2, (Q), cz, 0, 0, 0);    \
    f32x4 o3 = __builtin_amdgcn_mfma_f32_16x16x32_bf16(a3, (Q), cz, 0, 0, 0);    \
    _Pragma("unroll")                                                            \
    for (int r = 0; r < 4; ++r) {                                                \
        vm0[r] = fmaxf(vm0[r], o0[r]);                                           \
        vm1[r] = fmaxf(vm1[r], o1[r]);                                           \
        vm2[r] = fmaxf(vm2[r], o2[r]);                                           \
        vm3[r] = fmaxf(vm3[r], o3[r]);                                           \
    } }

// grid: (N/256=16, B=16, 2*JSPLIT=4)  z = d*2 + s. 1024 blocks = 4/CU.
// Wave: FOUR 16-i tiles (64 i), JCHUNK j's. Partial max -> vout (R8 path).
__global__ __launch_bounds__(BLK, 4)
void minmax_kernel(const uint4* __restrict__ A1u, const uint4* __restrict__ B1u,
                   const uint4* __restrict__ A2u, const uint4* __restrict__ B2u,
                   float* __restrict__ vout) {
    int z = blockIdx.z, b = blockIdx.y;
    int d = z >> 1, s = z & 1;
    const bf16x8* __restrict__ Aarr = (const bf16x8*)(d ? A2u : A1u);
    const bf16x8* __restrict__ Barr = (const bf16x8*)(d ? B1u : B2u);
    int tid = threadIdx.x;
    int L = tid & 63, w = tid >> 6;
    int lpt = L & 15, hi = (L >> 4) & 1;
    bool act = L < 32;                                 // k-groups 2,3 are zero
    int ibase = blockIdx.x * 256 + w * 64;             // i within batch row

    const bf16x8* pA = Aarr + (size_t)(b * N_ + ibase + lpt) * 2 + hi;
    const bf16x8* pB = Barr + (size_t)(b * N_ + s * JCHUNK + lpt) * 2 + hi;

    uint4 zu; zu.x = zu.y = zu.z = zu.w = 0u;
    bf16x8 zf = __builtin_bit_cast(bf16x8, zu);
    bf16x8 a0 = act ? pA[0] : zf;                      // i-tiles 0..3
    bf16x8 a1 = act ? pA[32] : zf;                     // (+16 pts * 2 each)
    bf16x8 a2 = act ? pA[64] : zf;
    bf16x8 a3 = act ? pA[96] : zf;
    f32x4 cz = {0.f, 0.f, 0.f, 0.f};
    f32x4 vm0 = {-3.0e38f, -3.0e38f, -3.0e38f, -3.0e38f};
    f32x4 vm1 = vm0, vm2 = vm0, vm3 = vm0;

    // 4-deep prefetch (R9 schedule): 4 loads in flight over 16 MFMA + 32 max3.
    bf16x8 p0 = pB[0], p1 = pB[32], p2 = pB[64], p3 = pB[96];
#pragma unroll 1
    for (int jt = 0; jt < JT2 - 4; jt += 4) {
        bf16x8 n0 = pB[(size_t)(jt + 4) * 32], n1 = pB[(size_t)(jt + 5) * 32];
        bf16x8 n2 = pB[(size_t)(jt + 6) * 32], n3 = pB[(size_t)(jt + 7) * 32];
        FOLDT(p0) FOLDT(p1) FOLDT(p2) FOLDT(p3)
        p0 = n0; p1 = n1; p2 = n2; p3 = n3;
    }
    FOLDT(p0) FOLDT(p1) FOLDT(p2) FOLDT(p3)

    // butterfly max across the 16 "col" (j) lanes — verified epilogue
#pragma unroll
    for (int off = 1; off < 16; off <<= 1)
#pragma unroll
        for (int r = 0; r < 4; ++r) {
            vm0[r] = fmaxf(vm0[r], __shfl_xor(vm0[r], off));
            vm1[r] = fmaxf(vm1[r], __shfl_xor(vm1[r], off));
            vm2[r] = fmaxf(vm2[r], __shfl_xor(vm2[r], off));
            vm3[r] = fmaxf(vm3[r], __shfl_xor(vm3[r], off));
        }
    if (lpt == 0) {
        int rg = L >> 4;                               // 0..3
#pragma unroll
        for (int r = 0; r < 4; ++r) {
            int row = rg * 4 + r;                      // 0..15 within tile
            int o = z * BN + b * N_ + ibase + row;
            vout[o] = vm0[r];
            vout[o + 16] = vm1[r];
            vout[o + 32] = vm2[r];
            vout[o + 48] = vm3[r];
        }
    }
}

__device__ inline float block_sum_256(float v, float* red4) {
    for (int off = 32; off; off >>= 1) v += __shfl_down(v, off, 64);
    int lane = threadIdx.x & 63, w = threadIdx.x >> 6;
    if (lane == 0) red4[w] = v;
    __syncthreads();
    return red4[0] + red4[1] + red4[2] + red4[3];
}

// combine j-splits (max), then sum: 256 blocks x 256 threads == BN (R8 path)
__global__ __launch_bounds__(BLK)
void reduce1_kernel(const float* __restrict__ vout, float* __restrict__ sums) {
    int t = blockIdx.x * BLK + threadIdx.x;
    float m0 = fmaxf(vout[t], vout[BN + t]);              // d=0: z=0,1
    float m1 = fmaxf(vout[2 * BN + t], vout[3 * BN + t]); // d=1: z=2,3
    float v = -2.0f * (m0 + m1);
    __shared__ float red4[4];
    float sm = block_sum_256(v, red4);
    if (threadIdx.x == 0) sums[blockIdx.x] = sm;
}

__global__ __launch_bounds__(BLK)
void reduce2_kernel(const float* __restrict__ sums, float* __restrict__ out) {
    float v = sums[threadIdx.x];
    __shared__ float red4[4];
    float sm = block_sum_256(v, red4);
    if (threadIdx.x == 0) out[0] = sm * (50.0f / (float)BN);
}

extern "C" void kernel_launch(void* const* d_in, const int* in_sizes, int n_in,
                              void* d_out, int out_size, void* d_ws, size_t ws_size,
                              hipStream_t stream) {
    const float* a1 = (const float*)d_in[0];
    const float* a2 = (const float*)d_in[1];
    char* ws = (char*)d_ws;
    uint4* A1 = (uint4*)(ws);                          // 2 MB each
    uint4* B1 = (uint4*)(ws + (2u << 20));
    uint4* A2 = (uint4*)(ws + (4u << 20));
    uint4* B2 = (uint4*)(ws + (6u << 20));
    float* vout = (float*)(ws + (8u << 20));           // 4*BN*4 = 1 MB
    float* sums = (float*)(ws + (9u << 20));           // 1 KB
    float* out = (float*)d_out;

    prep_kernel<<<dim3(BN / BLK, 2), BLK, 0, stream>>>(a1, a2, A1, B1, A2, B2);
    minmax_kernel<<<dim3(N_ / 256, B_, 2 * JSPLIT), BLK, 0, stream>>>(A1, B1, A2, B2, vout);
    reduce1_kernel<<<dim3(BN / BLK), BLK, 0, stream>>>(vout, sums);
    reduce2_kernel<<<dim3(1), BLK, 0, stream>>>(sums, out);
}